// Round 1
// baseline (1035.552 us; speedup 1.0000x reference)
//
#include <hip/hip_runtime.h>
#include <cstdint>
#include <cstddef>

typedef __attribute__((ext_vector_type(8))) short bf16x8;
typedef __attribute__((ext_vector_type(4))) float f32x4;

#define LO_OFF 184320  // elements per weight plane (hi plane size); lo plane follows

__device__ __forceinline__ unsigned short f2bf(float f) {
  union { float f; unsigned u; } c; c.f = f;
  unsigned u = c.u + 0x7fffu + ((c.u >> 16) & 1u);
  return (unsigned short)(u >> 16);
}
__device__ __forceinline__ float bf2f(unsigned short h) {
  union { unsigned u; float f; } c; c.u = ((unsigned)h) << 16;
  return c.f;
}

// ---------------- weight prep: fp32 [K][128] -> frag-linear split-bf16 ----------------
// frag-linear layout per matrix: elem((nt*KC + kc)*64 + lane)*8 + j  maps to
//   n = nt*16 + (lane&15),  k = kc*32 + (lane>>4)*8 + j   (zero-padded past K)
struct PrepP {
  const float* w[9];
  unsigned short* out;
};

__global__ __launch_bounds__(256) void prep_kernel(PrepP pp) {
  int gid = blockIdx.x * 256 + threadIdx.x;
  if (gid >= LO_OFF) return;
  const int Ks[9]  = {256,128,128, 256,128,128, 129,128,128};
  const int szs[9] = {32768,16384,16384, 32768,16384,16384, 20480,16384,16384};
  const int KCs[9] = {8,4,4, 8,4,4, 5,4,4};
  int m = 0, off = gid;
  while (m < 8 && off >= szs[m]) { off -= szs[m]; ++m; }
  int j    = off & 7;
  int t    = off >> 3;
  int lane = t & 63;
  int fc   = t >> 6;          // nt*KC + kc
  int KC   = KCs[m];
  int kc   = fc % KC;
  int nt   = fc / KC;
  int n = nt * 16 + (lane & 15);
  int k = kc * 32 + (lane >> 4) * 8 + j;
  float v = 0.f;
  if (k < Ks[m]) v = pp.w[m][(size_t)k * 128 + n];
  unsigned short hi = f2bf(v);
  unsigned short lo = f2bf(v - bf2f(hi));
  pp.out[gid] = hi;
  pp.out[LO_OFF + gid] = lo;
}

// ---------------- fused 3-layer MLP over gathered rows ----------------
struct FP {
  const float* srcA;     // mode0: x_in; mode1/2: xw
  const float* srcB;     // mode0: edge_features
  const float* addbase;  // mode2: bottom source (xw or x_in)
  const int* esrc;
  const int* edst;
  const float* est;
  const unsigned short* w0;
  const unsigned short* w1;
  const unsigned short* w2;
  const float* b0;
  const float* b1;
  const float* b2;
  float* out;
  int s, half, rows;
};

// one MFMA layer: A (split-bf16, LDS) x W (split-bf16, global frag-linear) -> relu -> split-bf16 back to LDS
template<int KC>
__device__ __forceinline__ void mfma_layer_to_h(
    char* AH, char* AL, int lane, int wrow0,
    const unsigned short* w, const float* bias) {
  bf16x8 ah[KC], al[KC];
  int arow = wrow0 + (lane & 15);
  int aswz = (arow & 7) << 4;
  #pragma unroll
  for (int kc = 0; kc < KC; ++kc) {
    int byt = (kc * 64 + (lane >> 4) * 16) ^ aswz;
    ah[kc] = *(const bf16x8*)(AH + arow * 512 + byt);
    al[kc] = *(const bf16x8*)(AL + arow * 512 + byt);
  }
  #pragma unroll
  for (int nt = 0; nt < 8; ++nt) {
    float bv = bias[nt * 16 + (lane & 15)];
    f32x4 acc = {bv, bv, bv, bv};
    #pragma unroll
    for (int kc = 0; kc < KC; ++kc) {
      const char* wb = (const char*)(w + (size_t)(nt * KC + kc) * 512) + lane * 16;
      bf16x8 bh = *(const bf16x8*)(wb);
      bf16x8 bl = *(const bf16x8*)(wb + (size_t)LO_OFF * 2);
      acc = __builtin_amdgcn_mfma_f32_16x16x32_bf16(ah[kc], bh, acc, 0, 0, 0);
      acc = __builtin_amdgcn_mfma_f32_16x16x32_bf16(ah[kc], bl, acc, 0, 0, 0);
      acc = __builtin_amdgcn_mfma_f32_16x16x32_bf16(al[kc], bh, acc, 0, 0, 0);
    }
    #pragma unroll
    for (int r = 0; r < 4; ++r) {
      float v = fmaxf(acc[r], 0.f);
      int row = wrow0 + (lane >> 4) * 4 + r;
      int cb = (nt * 32 + (lane & 15) * 2) ^ ((row & 7) << 4);
      unsigned short hv = f2bf(v);
      *(unsigned short*)(AH + row * 512 + cb) = hv;
      *(unsigned short*)(AL + row * 512 + cb) = f2bf(v - bf2f(hv));
    }
  }
}

__device__ __forceinline__ void stage_write(char* AH, char* AL, int row, int byt, float4 v) {
  unsigned short h0 = f2bf(v.x), h1 = f2bf(v.y), h2 = f2bf(v.z), h3 = f2bf(v.w);
  uint2 hw, lw;
  hw.x = (unsigned)h0 | ((unsigned)h1 << 16);
  hw.y = (unsigned)h2 | ((unsigned)h3 << 16);
  lw.x = (unsigned)f2bf(v.x - bf2f(h0)) | ((unsigned)f2bf(v.y - bf2f(h1)) << 16);
  lw.y = (unsigned)f2bf(v.z - bf2f(h2)) | ((unsigned)f2bf(v.w - bf2f(h3)) << 16);
  *(uint2*)(AH + row * 512 + byt) = hw;
  *(uint2*)(AL + row * 512 + byt) = lw;
}

// MODE 0: leaf embed  in = [x_in[esrc[e]], ef[e]]           out -> xw[edst[e]]
// MODE 1: up merge    in = [xw[esrc[s+i]], xw[esrc[s+half+i]]] out -> xw[edst[s+i]]
// MODE 2: down        in = [xw[edst[s+e]], state, 0pad]     out -> xw[esrc[s+e]] += bottom
template<int MODE>
__global__ __launch_bounds__(256) void fused_mlp(FP p) {
  __shared__ char AH[64 * 512];
  __shared__ char AL[64 * 512];
  const int tid = threadIdx.x;
  const int wid = tid >> 6;
  const int lane = tid & 63;
  const int tbase = blockIdx.x * 64;
  const int wrow0 = wid * 16;

  // ---- stage this wave's 16 rows (split-bf16, swizzled) ----
  if (MODE != 2) {
    #pragma unroll
    for (int it = 0; it < 16; ++it) {
      int row = wrow0 + it;
      int rg = tbase + row;
      int f4 = lane;
      float4 v = {0.f, 0.f, 0.f, 0.f};
      if (rg < p.rows) {
        if (MODE == 0) {
          if (f4 < 32) { int node = p.esrc[rg]; v = *(const float4*)(p.srcA + (size_t)node * 128 + f4 * 4); }
          else         { v = *(const float4*)(p.srcB + (size_t)rg * 128 + (f4 - 32) * 4); }
        } else {
          if (f4 < 32) { int node = p.esrc[p.s + rg];          v = *(const float4*)(p.srcA + (size_t)node * 128 + f4 * 4); }
          else         { int node = p.esrc[p.s + p.half + rg]; v = *(const float4*)(p.srcA + (size_t)node * 128 + (f4 - 32) * 4); }
        }
      }
      int byt = (f4 * 8) ^ ((row & 7) << 4);
      stage_write(AH, AL, row, byt, v);
    }
  } else {
    #pragma unroll
    for (int it = 0; it < 8; ++it) {
      int li = it * 64 + lane;
      int rl = li >> 5;
      int f4 = li & 31;
      int row = wrow0 + rl;
      int rg = tbase + row;
      float4 v = {0.f, 0.f, 0.f, 0.f};
      if (rg < p.rows) { int node = p.edst[p.s + rg]; v = *(const float4*)(p.srcA + (size_t)node * 128 + f4 * 4); }
      int byt = (f4 * 8) ^ ((row & 7) << 4);
      stage_write(AH, AL, row, byt, v);
    }
    { // k in [128,160): state at k=128, zeros elsewhere
      int rl = lane >> 2;
      int ci = lane & 3;
      int row = wrow0 + rl;
      int rg = tbase + row;
      float sv = (rg < p.rows && ci == 0) ? p.est[p.s + rg] : 0.f;
      uint4 hz = {0u, 0u, 0u, 0u};
      uint4 lz = {0u, 0u, 0u, 0u};
      hz.x = (unsigned)f2bf(sv);     // state is 0.0/1.0 -> exact in bf16, lo = 0
      int byt = (256 + ci * 16) ^ ((row & 7) << 4);
      *(uint4*)(AH + row * 512 + byt) = hz;
      *(uint4*)(AL + row * 512 + byt) = lz;
    }
  }
  __syncthreads();

  constexpr int KC0 = (MODE == 2) ? 5 : 8;
  mfma_layer_to_h<KC0>(AH, AL, lane, wrow0, p.w0, p.b0);
  __syncthreads();
  mfma_layer_to_h<4>(AH, AL, lane, wrow0, p.w1, p.b1);
  __syncthreads();

  // ---- layer 2 (no relu) + epilogue scatter ----
  {
    bf16x8 ah[4], al[4];
    int arow = wrow0 + (lane & 15);
    int aswz = (arow & 7) << 4;
    #pragma unroll
    for (int kc = 0; kc < 4; ++kc) {
      int byt = (kc * 64 + (lane >> 4) * 16) ^ aswz;
      ah[kc] = *(const bf16x8*)(AH + arow * 512 + byt);
      al[kc] = *(const bf16x8*)(AL + arow * 512 + byt);
    }
    int nodes[4]; bool vld[4];
    #pragma unroll
    for (int r = 0; r < 4; ++r) {
      int rg = tbase + wrow0 + (lane >> 4) * 4 + r;
      vld[r] = rg < p.rows;
      int e = 0;
      if (vld[r]) {
        if (MODE == 0)      e = p.edst[rg];
        else if (MODE == 1) e = p.edst[p.s + rg];
        else                e = p.esrc[p.s + rg];
      }
      nodes[r] = e;
    }
    #pragma unroll
    for (int nt = 0; nt < 8; ++nt) {
      float bv = p.b2[nt * 16 + (lane & 15)];
      f32x4 acc = {bv, bv, bv, bv};
      #pragma unroll
      for (int kc = 0; kc < 4; ++kc) {
        const char* wb = (const char*)(p.w2 + (size_t)(nt * 4 + kc) * 512) + lane * 16;
        bf16x8 bh = *(const bf16x8*)(wb);
        bf16x8 bl = *(const bf16x8*)(wb + (size_t)LO_OFF * 2);
        acc = __builtin_amdgcn_mfma_f32_16x16x32_bf16(ah[kc], bh, acc, 0, 0, 0);
        acc = __builtin_amdgcn_mfma_f32_16x16x32_bf16(ah[kc], bl, acc, 0, 0, 0);
        acc = __builtin_amdgcn_mfma_f32_16x16x32_bf16(al[kc], bh, acc, 0, 0, 0);
      }
      int col = nt * 16 + (lane & 15);
      #pragma unroll
      for (int r = 0; r < 4; ++r) {
        if (vld[r]) {
          float v = acc[r];
          if (MODE == 2) v += p.addbase[(size_t)nodes[r] * 128 + col];
          p.out[(size_t)nodes[r] * 128 + col] = v;
        }
      }
    }
  }
}

extern "C" void kernel_launch(void* const* d_in, const int* in_sizes, int n_in,
                              void* d_out, int out_size, void* d_ws, size_t ws_size,
                              hipStream_t stream) {
  const float* xin  = (const float*)d_in[0];
  const int*   esrc = (const int*)d_in[1];
  const int*   edst = (const int*)d_in[2];
  const float* est  = (const float*)d_in[3];
  const float* ef   = (const float*)d_in[4];
  unsigned short* wsb = (unsigned short*)d_ws;
  float* xw = (float*)d_out;

  // ---- weight prep ----
  PrepP pp;
  const int widx[9] = {6, 8, 10, 12, 14, 16, 18, 20, 22};
  for (int i = 0; i < 9; ++i) pp.w[i] = (const float*)d_in[widx[i]];
  pp.out = wsb;
  prep_kernel<<<dim3(720), dim3(256), 0, stream>>>(pp);

  // edge-block geometry (B=8, D=14, N_LEAF=8192 -> nL=65536) — compile-time fixed
  int blk[14], off[14];
  blk[0] = 65536; off[0] = 0;
  for (int d = 1; d <= 13; ++d) { blk[d] = 65536 >> (d - 1); off[d] = off[d - 1] + blk[d - 1]; }

  auto fill = [&](FP& p, int s, int half, int rows, const float* addb,
                  int w0o, int w1o, int w2o, int b0i, int b1i, int b2i) {
    p.addbase = addb;
    p.esrc = esrc; p.edst = edst; p.est = est;
    p.w0 = wsb + w0o; p.w1 = wsb + w1o; p.w2 = wsb + w2o;
    p.b0 = (const float*)d_in[b0i]; p.b1 = (const float*)d_in[b1i]; p.b2 = (const float*)d_in[b2i];
    p.out = xw;
    p.s = s; p.half = half; p.rows = rows;
  };

  // phase 1: leaf embed (nem), 65536 rows
  {
    FP p; p.srcA = xin; p.srcB = ef;
    fill(p, 0, 0, 65536, nullptr, 0, 32768, 49152, 7, 9, 11);
    fused_mlp<0><<<dim3(1024), dim3(256), 0, stream>>>(p);
  }
  // phase 2: upward merge (mg), levels d=1..13
  for (int d = 1; d <= 13; ++d) {
    FP p; p.srcA = xw; p.srcB = xw;
    int rows = blk[d] / 2;
    fill(p, off[d], rows, rows, nullptr, 65536, 98304, 114688, 13, 15, 17);
    fused_mlp<1><<<dim3((rows + 63) / 64), dim3(256), 0, stream>>>(p);
  }
  // phase 3: downward (mr), blocks 13..0
  for (int bi = 13; bi >= 0; --bi) {
    FP p; p.srcA = xw; p.srcB = xw;
    int rows = blk[bi];
    const float* addb = (bi == 0) ? xin : xw;
    fill(p, off[bi], 0, rows, addb, 131072, 151552, 167936, 19, 21, 23);
    fused_mlp<2><<<dim3((rows + 63) / 64), dim3(256), 0, stream>>>(p);
  }
}

// Round 2
// 982.317 us; speedup vs baseline: 1.0542x; 1.0542x over previous
//
#include <hip/hip_runtime.h>
#include <cstdint>
#include <cstddef>

typedef __attribute__((ext_vector_type(8))) short bf16x8;
typedef __attribute__((ext_vector_type(4))) float f32x4;
typedef unsigned short u16;

#define LO_OFF 184320
#define MFMA16(a,b,c) __builtin_amdgcn_mfma_f32_16x16x32_bf16((a),(b),(c),0,0,0)

__device__ __forceinline__ u16 f2bf(float f) {
  union { float f; unsigned u; } c; c.f = f;
  unsigned u = c.u + 0x7fffu + ((c.u >> 16) & 1u);
  return (u16)(u >> 16);
}
__device__ __forceinline__ float bf2f(u16 h) {
  union { unsigned u; float f; } c; c.u = ((unsigned)h) << 16;
  return c.f;
}
__device__ __forceinline__ void split4(float4 v, uint2& hw, uint2& lw) {
  u16 h0 = f2bf(v.x), h1 = f2bf(v.y), h2 = f2bf(v.z), h3 = f2bf(v.w);
  hw.x = (unsigned)h0 | ((unsigned)h1 << 16);
  hw.y = (unsigned)h2 | ((unsigned)h3 << 16);
  lw.x = (unsigned)f2bf(v.x - bf2f(h0)) | ((unsigned)f2bf(v.y - bf2f(h1)) << 16);
  lw.y = (unsigned)f2bf(v.z - bf2f(h2)) | ((unsigned)f2bf(v.w - bf2f(h3)) << 16);
}

// ---------------- weight prep: fp32 [K][128] -> frag-linear split-bf16 ----------------
struct PrepP {
  const float* w[9];
  u16* out;
};

__global__ __launch_bounds__(256) void prep_kernel(PrepP pp) {
  int gid = blockIdx.x * 256 + threadIdx.x;
  if (gid >= LO_OFF) return;
  const int Ks[9]  = {256,128,128, 256,128,128, 129,128,128};
  const int szs[9] = {32768,16384,16384, 32768,16384,16384, 20480,16384,16384};
  const int KCs[9] = {8,4,4, 8,4,4, 5,4,4};
  int m = 0, off = gid;
  while (m < 8 && off >= szs[m]) { off -= szs[m]; ++m; }
  int j    = off & 7;
  int t    = off >> 3;
  int lane = t & 63;
  int fc   = t >> 6;          // nt*KC + kc
  int KC   = KCs[m];
  int kc   = fc % KC;
  int nt   = fc / KC;
  int n = nt * 16 + (lane & 15);
  int k = kc * 32 + (lane >> 4) * 8 + j;
  float v = 0.f;
  if (k < Ks[m]) v = pp.w[m][(size_t)k * 128 + n];
  u16 hi = f2bf(v);
  u16 lo = f2bf(v - bf2f(hi));
  pp.out[gid] = hi;
  pp.out[LO_OFF + gid] = lo;
}

// ---------------- per-level params ----------------
struct LP {
  const float* srcA; const float* srcB; const float* addb;
  const int* esrc; const int* edst; const float* est;
  const u16 *w0, *w1, *w2;
  const float *b0, *b1, *b2;
  float* out;
  int s, half, rows;
};

// one mid layer: A(split-bf16 LDS, LDA bytes/row) x W(frag-linear global) -> relu -> split to O ([16][128], 256B/row)
template<int KC, int LDA>
__device__ __forceinline__ void layer_mid(const u16* AH, const u16* AL, u16* OH, u16* OL,
                                          int lane, int wv, const u16* wgt, const float* bias) {
  const int arow = lane & 15;
  const int g = lane >> 4;
  const int aswz = (arow & 7) << 4;
  const char* ahb = (const char*)AH + arow * LDA;
  const char* alb = (const char*)AL + arow * LDA;
  const int nt0 = wv * 2;
  float bv0 = bias[nt0 * 16 + arow];
  float bv1 = bias[nt0 * 16 + 16 + arow];
  f32x4 acc0 = {bv0, bv0, bv0, bv0};
  f32x4 acc1 = {bv1, bv1, bv1, bv1};
  #pragma unroll
  for (int kc = 0; kc < KC; ++kc) {
    int byt = (kc * 64 + g * 16) ^ aswz;
    bf16x8 ah = *(const bf16x8*)(ahb + byt);
    bf16x8 al = *(const bf16x8*)(alb + byt);
    const u16* wb0 = wgt + (size_t)(nt0 * KC + kc) * 512 + lane * 8;
    const u16* wb1 = wb0 + (size_t)KC * 512;
    bf16x8 bh0 = *(const bf16x8*)wb0;
    bf16x8 bl0 = *(const bf16x8*)(wb0 + LO_OFF);
    bf16x8 bh1 = *(const bf16x8*)wb1;
    bf16x8 bl1 = *(const bf16x8*)(wb1 + LO_OFF);
    acc0 = MFMA16(ah, bh0, acc0); acc1 = MFMA16(ah, bh1, acc1);
    acc0 = MFMA16(ah, bl0, acc0); acc1 = MFMA16(ah, bl1, acc1);
    acc0 = MFMA16(al, bh0, acc0); acc1 = MFMA16(al, bh1, acc1);
  }
  #pragma unroll
  for (int r = 0; r < 4; ++r) {
    int row = g * 4 + r;
    int oswz = (row & 7) << 4;
    char* oh = (char*)OH + row * 256;
    char* ol = (char*)OL + row * 256;
    float v0 = fmaxf(acc0[r], 0.f);
    float v1 = fmaxf(acc1[r], 0.f);
    int c0 = ((nt0 * 16 + arow) * 2) ^ oswz;
    int c1 = ((nt0 * 16 + 16 + arow) * 2) ^ oswz;
    u16 h0 = f2bf(v0), h1 = f2bf(v1);
    *(u16*)(oh + c0) = h0; *(u16*)(ol + c0) = f2bf(v0 - bf2f(h0));
    *(u16*)(oh + c1) = h1; *(u16*)(ol + c1) = f2bf(v1 - bf2f(h1));
  }
}

// final layer (no relu) + scatter to global (+ residual add for MODE 2)
template<int MODE>
__device__ __forceinline__ void layer_out(const u16* AH, const u16* AL,
                                          int lane, int wv, const LP& p, int tbase) {
  const int arow = lane & 15;
  const int g = lane >> 4;
  const int aswz = (arow & 7) << 4;
  const char* ahb = (const char*)AH + arow * 256;
  const char* alb = (const char*)AL + arow * 256;
  const int nt0 = wv * 2;
  float bv0 = p.b2[nt0 * 16 + arow];
  float bv1 = p.b2[nt0 * 16 + 16 + arow];
  f32x4 acc0 = {bv0, bv0, bv0, bv0};
  f32x4 acc1 = {bv1, bv1, bv1, bv1};

  int nodes[4]; bool vld[4];
  #pragma unroll
  for (int r = 0; r < 4; ++r) {
    int rg = tbase + g * 4 + r;
    vld[r] = rg < p.rows;
    int e = 0;
    if (vld[r]) e = (MODE == 2) ? p.esrc[p.s + rg]
                 : ((MODE == 0) ? p.edst[rg] : p.edst[p.s + rg]);
    nodes[r] = e;
  }
  #pragma unroll
  for (int kc = 0; kc < 4; ++kc) {
    int byt = (kc * 64 + g * 16) ^ aswz;
    bf16x8 ah = *(const bf16x8*)(ahb + byt);
    bf16x8 al = *(const bf16x8*)(alb + byt);
    const u16* wb0 = p.w2 + (size_t)(nt0 * 4 + kc) * 512 + lane * 8;
    const u16* wb1 = wb0 + (size_t)4 * 512;
    bf16x8 bh0 = *(const bf16x8*)wb0;
    bf16x8 bl0 = *(const bf16x8*)(wb0 + LO_OFF);
    bf16x8 bh1 = *(const bf16x8*)wb1;
    bf16x8 bl1 = *(const bf16x8*)(wb1 + LO_OFF);
    acc0 = MFMA16(ah, bh0, acc0); acc1 = MFMA16(ah, bh1, acc1);
    acc0 = MFMA16(ah, bl0, acc0); acc1 = MFMA16(ah, bl1, acc1);
    acc0 = MFMA16(al, bh0, acc0); acc1 = MFMA16(al, bh1, acc1);
  }
  int col0 = nt0 * 16 + arow, col1 = col0 + 16;
  #pragma unroll
  for (int r = 0; r < 4; ++r) {
    if (vld[r]) {
      float v0 = acc0[r], v1 = acc1[r];
      size_t b = (size_t)nodes[r] * 128;
      if (MODE == 2) { v0 += p.addb[b + col0]; v1 += p.addb[b + col1]; }
      p.out[b + col0] = v0;
      p.out[b + col1] = v1;
    }
  }
}

// 16-row 3-layer MLP tile; 4 waves, each wave: all 16 rows x 2 n-tiles
// MODE 0: leaf embed, MODE 1: up merge, MODE 2: down
template<int MODE>
__device__ __forceinline__ void mlp_tile(u16* SH, u16* SL, u16* HH, u16* HL,
                                         const LP& p, int tbase) {
  const int tid = threadIdx.x;
  const int lane = tid & 63;
  const int wv = tid >> 6;
  {
    int row = tid >> 4, q = tid & 15;
    int rg = tbase + row;
    int swz = (row & 7) << 4;
    char* sh = (char*)SH + row * 512;
    char* sl = (char*)SL + row * 512;
    bool ok = rg < p.rows;
    if (MODE != 2) {
      const float* pL = nullptr; const float* pR = nullptr;
      if (ok) {
        if (MODE == 0) { pL = p.srcA + (size_t)p.esrc[rg] * 128; pR = p.srcB + (size_t)rg * 128; }
        else           { pL = p.srcA + (size_t)p.esrc[p.s + rg] * 128;
                         pR = p.srcA + (size_t)p.esrc[p.s + p.half + rg] * 128; }
      }
      #pragma unroll
      for (int i = 0; i < 4; ++i) {
        int f4 = q * 4 + i;
        float4 v = {0.f, 0.f, 0.f, 0.f};
        if (ok) v = (f4 < 32) ? *(const float4*)(pL + f4 * 4) : *(const float4*)(pR + (f4 - 32) * 4);
        uint2 hw, lw; split4(v, hw, lw);
        int byt = (f4 * 8) ^ swz;
        *(uint2*)(sh + byt) = hw; *(uint2*)(sl + byt) = lw;
      }
    } else {
      const float* pT = ok ? p.srcA + (size_t)p.edst[p.s + rg] * 128 : nullptr;
      #pragma unroll
      for (int i = 0; i < 2; ++i) {
        int f4 = q * 2 + i;
        float4 v = {0.f, 0.f, 0.f, 0.f};
        if (ok) v = *(const float4*)(pT + f4 * 4);
        uint2 hw, lw; split4(v, hw, lw);
        int byt = (f4 * 8) ^ swz;
        *(uint2*)(sh + byt) = hw; *(uint2*)(sl + byt) = lw;
      }
      if (q < 4) {   // k in [128,160): state at k=128, zeros elsewhere
        float sv = (q == 0 && ok) ? p.est[p.s + rg] : 0.f;
        uint4 hz = {0u, 0u, 0u, 0u}, lz = {0u, 0u, 0u, 0u};
        hz.x = (unsigned)f2bf(sv);
        int byt = (256 + q * 16) ^ swz;
        *(uint4*)(sh + byt) = hz;
        *(uint4*)(sl + byt) = lz;
      }
    }
  }
  __syncthreads();
  layer_mid<(MODE == 2 ? 5 : 8), 512>(SH, SL, HH, HL, lane, wv, p.w0, p.b0);
  __syncthreads();
  layer_mid<4, 256>(HH, HL, SH, SL, lane, wv, p.w1, p.b1);
  __syncthreads();
  layer_out<MODE>(SH, SL, lane, wv, p, tbase);
}

template<int MODE>
__global__ __launch_bounds__(256) void level_kernel(LP p) {
  __shared__ u16 SH[16 * 256];
  __shared__ u16 SL[16 * 256];
  __shared__ u16 HH[16 * 128];
  __shared__ u16 HL[16 * 128];
  mlp_tile<MODE>(SH, SL, HH, HL, p, blockIdx.x * 16);
}

// ---------------- fused multi-level kernel (tiny levels) ----------------
struct GP {
  const int* esrc; const int* edst; const float* est;
  float* xw;
  const u16 *gw0, *gw1, *gw2; const float *gb0, *gb1, *gb2;   // mg
  const u16 *rw0, *rw1, *rw2; const float *rb0, *rb1, *rb2;   // mr
  unsigned* cnt;
  int nlev;
  int mode[17]; int s[17]; int rows[17];
};

__global__ __launch_bounds__(256) void fused_kernel(GP g) {
  __shared__ u16 SH[16 * 256];
  __shared__ u16 SL[16 * 256];
  __shared__ u16 HH[16 * 128];
  __shared__ u16 HL[16 * 128];
  const unsigned nb = gridDim.x;
  for (int li = 0; li < g.nlev; ++li) {
    int rows = g.rows[li];
    int tbase = blockIdx.x * 16;
    if (tbase < rows) {
      LP p;
      p.esrc = g.esrc; p.edst = g.edst; p.est = g.est;
      p.srcA = g.xw; p.srcB = g.xw; p.addb = g.xw; p.out = g.xw;
      p.s = g.s[li]; p.half = rows; p.rows = rows;
      if (g.mode[li] == 1) {
        p.w0 = g.gw0; p.w1 = g.gw1; p.w2 = g.gw2; p.b0 = g.gb0; p.b1 = g.gb1; p.b2 = g.gb2;
        mlp_tile<1>(SH, SL, HH, HL, p, tbase);
      } else {
        p.w0 = g.rw0; p.w1 = g.rw1; p.w2 = g.rw2; p.b0 = g.rb0; p.b1 = g.rb1; p.b2 = g.rb2;
        mlp_tile<2>(SH, SL, HH, HL, p, tbase);
      }
    }
    // device-scope barrier across all blocks
    __syncthreads();
    if (threadIdx.x == 0) {
      __threadfence();
      __hip_atomic_fetch_add(g.cnt + li, 1u, __ATOMIC_ACQ_REL, __HIP_MEMORY_SCOPE_AGENT);
      while (__hip_atomic_load(g.cnt + li, __ATOMIC_ACQUIRE, __HIP_MEMORY_SCOPE_AGENT) < nb) {
        __builtin_amdgcn_s_sleep(2);
      }
    }
    __syncthreads();
  }
}

extern "C" void kernel_launch(void* const* d_in, const int* in_sizes, int n_in,
                              void* d_out, int out_size, void* d_ws, size_t ws_size,
                              hipStream_t stream) {
  const float* xin  = (const float*)d_in[0];
  const int*   esrc = (const int*)d_in[1];
  const int*   edst = (const int*)d_in[2];
  const float* est  = (const float*)d_in[3];
  const float* ef   = (const float*)d_in[4];
  u16* wsb = (u16*)d_ws;
  float* xw = (float*)d_out;
  unsigned* cnt = (unsigned*)((char*)d_ws + 737280);   // after 2-plane weight region

  // ---- weight prep ----
  PrepP pp;
  const int widx[9] = {6, 8, 10, 12, 14, 16, 18, 20, 22};
  for (int i = 0; i < 9; ++i) pp.w[i] = (const float*)d_in[widx[i]];
  pp.out = wsb;
  prep_kernel<<<dim3(720), dim3(256), 0, stream>>>(pp);
  hipMemsetAsync(cnt, 0, 128, stream);

  // edge-block geometry (B=8, D=14, N_LEAF=8192 -> nL=65536)
  int blk[14], off[14];
  blk[0] = 65536; off[0] = 0;
  for (int d = 1; d <= 13; ++d) { blk[d] = 65536 >> (d - 1); off[d] = off[d - 1] + blk[d - 1]; }

  auto base = [&](LP& p) {
    p.esrc = esrc; p.edst = edst; p.est = est; p.out = xw;
    p.srcA = xw; p.srcB = xw; p.addb = xw;
  };

  // phase 1: leaf embed (nem)
  {
    LP p; base(p);
    p.srcA = xin; p.srcB = ef;
    p.w0 = wsb + 0; p.w1 = wsb + 32768; p.w2 = wsb + 49152;
    p.b0 = (const float*)d_in[7]; p.b1 = (const float*)d_in[9]; p.b2 = (const float*)d_in[11];
    p.s = 0; p.half = 0; p.rows = 65536;
    level_kernel<0><<<dim3(4096), dim3(256), 0, stream>>>(p);
  }
  // phase 2: upward merge (mg), big levels d=1..4
  for (int d = 1; d <= 4; ++d) {
    LP p; base(p);
    int rows = blk[d] / 2;
    p.w0 = wsb + 65536; p.w1 = wsb + 98304; p.w2 = wsb + 114688;
    p.b0 = (const float*)d_in[13]; p.b1 = (const float*)d_in[15]; p.b2 = (const float*)d_in[17];
    p.s = off[d]; p.half = rows; p.rows = rows;
    level_kernel<1><<<dim3((rows + 15) / 16), dim3(256), 0, stream>>>(p);
  }
  // fused tiny levels: up d=5..13, then down bi=13..6
  {
    GP g;
    g.esrc = esrc; g.edst = edst; g.est = est; g.xw = xw; g.cnt = cnt;
    g.gw0 = wsb + 65536; g.gw1 = wsb + 98304; g.gw2 = wsb + 114688;
    g.gb0 = (const float*)d_in[13]; g.gb1 = (const float*)d_in[15]; g.gb2 = (const float*)d_in[17];
    g.rw0 = wsb + 131072; g.rw1 = wsb + 151552; g.rw2 = wsb + 167936;
    g.rb0 = (const float*)d_in[19]; g.rb1 = (const float*)d_in[21]; g.rb2 = (const float*)d_in[23];
    int li = 0;
    for (int d = 5; d <= 13; ++d) { g.mode[li] = 1; g.s[li] = off[d]; g.rows[li] = blk[d] / 2; ++li; }
    for (int bi = 13; bi >= 6; --bi) { g.mode[li] = 2; g.s[li] = off[bi]; g.rows[li] = blk[bi]; ++li; }
    g.nlev = li;  // 17, max rows 2048 -> 128 blocks
    fused_kernel<<<dim3(128), dim3(256), 0, stream>>>(g);
  }
  // phase 3: downward (mr), big levels bi=5..0
  for (int bi = 5; bi >= 0; --bi) {
    LP p; base(p);
    int rows = blk[bi];
    p.addb = (bi == 0) ? xin : xw;
    p.w0 = wsb + 131072; p.w1 = wsb + 151552; p.w2 = wsb + 167936;
    p.b0 = (const float*)d_in[19]; p.b1 = (const float*)d_in[21]; p.b2 = (const float*)d_in[23];
    p.s = off[bi]; p.half = 0; p.rows = rows;
    level_kernel<2><<<dim3((rows + 15) / 16), dim3(256), 0, stream>>>(p);
  }
}